// Round 4
// baseline (1446.465 us; speedup 1.0000x reference)
//
#include <hip/hip_runtime.h>
#include <cstdint>

#define NB 256
#define NT 128
#define NS 128
#define NH 256

#define NTHR 512
#define NWG  256
#define GPW  8      // wgs per group
#define NGRP 32
#define GBAT 8      // batch elems per group
#define UPW  32     // hidden units per wg
#define RPW  128    // gate rows per wg
#define TPW  16     // W_ah rows per wg

// ws layout in uint32 words
#define HC_OFF  0        // [2][32][8 gid][8 b][32 u] = 131072 words (f16x2 h,c)
#define SP_OFF  131072   // [32][8 gid][128 n][4 bq]  = 131072 words (f16x2 sp_b, sp_b+4)
#define E_OFF   262144   // [32][8 b][128 n] f32      = 32768 words
#define CNT_OFF 294912   // [32][16] counters: [0]=pre [1]=c1 [2]=c2

typedef _Float16 f16;
typedef _Float16 f16x2 __attribute__((ext_vector_type(2)));

__device__ __forceinline__ float dot2f(f16x2 a, f16x2 b, float c) {
#if defined(__has_builtin) && __has_builtin(__builtin_amdgcn_fdot2)
  return __builtin_amdgcn_fdot2(a, b, c, false);
#else
  return c + (float)a.x * (float)b.x + (float)a.y * (float)b.y;
#endif
}
__device__ __forceinline__ f16x2 pk(float a, float b) {
  f16x2 r; r.x = (f16)a; r.y = (f16)b; return r;
}
__device__ __forceinline__ void awr(uint32_t* p, uint32_t v) {
  __hip_atomic_store(p, v, __ATOMIC_RELAXED, __HIP_MEMORY_SCOPE_AGENT);
}
__device__ __forceinline__ uint32_t ard(uint32_t* p) {
  return __hip_atomic_load(p, __ATOMIC_RELAXED, __HIP_MEMORY_SCOPE_AGENT);
}
__device__ __forceinline__ void cinc(uint32_t* p) {
  __hip_atomic_fetch_add(p, 1u, __ATOMIC_RELAXED, __HIP_MEMORY_SCOPE_AGENT);
}
__device__ __forceinline__ void cwait(uint32_t* p, uint32_t tgt) {
  while (ard(p) < tgt) __builtin_amdgcn_s_sleep(2);
}

struct __align__(16) Sm {
  f16   WG[RPW * 384];      // 98304 B gate weights, chunk-XOR swizzled by row
  f16   WA[TPW * 512];      // 16384 B W_ah slice, chunk-XOR swizzled
  f16   hch[GBAT][520];     // [h(0:256)|c(256:512)], padded stride
  f16   act[GBAT][392];     // [wx(0:128)|h(128:384)], padded stride
  float E[GBAT][128];
  float Pown[TPW][GBAT];
  float gacc[RPW][GBAT];
  float cbuf[UPW][GBAT];
  float gbias[RPW];
  float w2a[TPW];
  float bah[TPW];
  float S0s;
};

__global__ void enc_init(uint32_t* ws) {
  int i = blockIdx.x * blockDim.x + threadIdx.x;
  if (i < 65536) ws[HC_OFF + i] = 0u;     // zero h,c parity 0
  if (i < 512)   ws[CNT_OFF + i] = 0u;    // zero counters
}

__global__ __launch_bounds__(NTHR, 2) void enc_main(
    const float* __restrict__ x,    const float* __restrict__ W_ah,
    const float* __restrict__ b_ah, const float* __restrict__ W_ai,
    const float* __restrict__ b_ai, const float* __restrict__ W_a,
    const float* __restrict__ b_a,  const float* __restrict__ W_ih,
    const float* __restrict__ W_hh, const float* __restrict__ b_ih,
    const float* __restrict__ b_hh, float* __restrict__ out_iw,
    float* __restrict__ out_ie,     uint32_t* __restrict__ ws)
{
  __shared__ Sm sm;
  const int tid  = threadIdx.x;
  const int wg   = blockIdx.x;
  const int xcd  = wg & 7, slot = wg >> 3;
  const int g    = xcd * 4 + (slot >> 3);   // group 0..31 (members co-XCD if round-robin; perf-only)
  const int gid  = slot & 7;                // member 0..7
  const int bbase = g * GBAT;
  const int u0    = gid * UPW;

  uint32_t* cnt_pre = ws + CNT_OFF + g * 16 + 0;
  uint32_t* cnt1    = ws + CNT_OFF + g * 16 + 1;
  uint32_t* cnt2    = ws + CNT_OFF + g * 16 + 2;

  // ---- stage gate-weight slice (128 rows x 384 cols, f16, swizzled) ----
  #pragma unroll
  for (int i = 0; i < 12; ++i) {
    int idx = i * NTHR + tid;            // 6144 chunks of 8 f16
    int r = idx / 48, c = idx % 48;
    int grow = (r >> 5) * 256 + u0 + (r & 31);
    const float* src = (c < 16) ? (W_ih + (size_t)grow * NS + c * 8)
                                : (W_hh + (size_t)grow * NH + (c - 16) * 8);
    float4 v0 = *(const float4*)src;
    float4 v1 = *(const float4*)(src + 4);
    f16x2 t4[4] = { pk(v0.x, v0.y), pk(v0.z, v0.w), pk(v1.x, v1.y), pk(v1.z, v1.w) };
    *(float4*)&sm.WG[((size_t)r * 48 + (c ^ (r & 7))) * 8] = *(float4*)t4;
  }
  // ---- stage W_ah slice (16 rows x 512 cols) ----
  #pragma unroll
  for (int i = 0; i < 2; ++i) {
    int idx = i * NTHR + tid;            // 1024 chunks
    int lt = idx >> 6, c = idx & 63;
    const float* src = W_ah + (size_t)(gid * TPW + lt) * 512 + c * 8;
    float4 v0 = *(const float4*)src;
    float4 v1 = *(const float4*)(src + 4);
    f16x2 t4[4] = { pk(v0.x, v0.y), pk(v0.z, v0.w), pk(v1.x, v1.y), pk(v1.z, v1.w) };
    *(float4*)&sm.WA[((size_t)lt * 64 + (c ^ (lt & 7))) * 8] = *(float4*)t4;
  }
  if (tid < RPW) {
    int grow = (tid >> 5) * 256 + u0 + (tid & 31);
    sm.gbias[tid] = b_ih[grow] + b_hh[grow];
  }
  if (tid < TPW) {
    sm.w2a[tid] = 2.f * W_a[gid * TPW + tid];
    sm.bah[tid] = b_ah[gid * TPW + tid];
  }
  if (tid < 256) sm.cbuf[tid >> 3][tid & 7] = 0.f;
  if (tid == 0) { float s = b_a[0]; for (int i = 0; i < 128; ++i) s += W_a[i]; sm.S0s = s; }

  // ---- E for own batch elem (b = bbase+gid), publish, group barrier ----
  {
    int n = tid >> 2, ks = tid & 3;
    const float* xb = x + (size_t)(bbase + gid) * NT * NS;
    float a = 0.f;
    for (int tt = ks * 32; tt < ks * 32 + 32; ++tt)
      a = fmaf(xb[(size_t)tt * NS + n], W_ai[tt], a);
    a += __shfl_xor(a, 1); a += __shfl_xor(a, 2);
    if (ks == 0) {
      float e = __expf(2.f * (a + b_ai[0]));
      awr(ws + E_OFF + ((size_t)g * 8 + gid) * 128 + n, __builtin_bit_cast(uint32_t, e));
    }
  }
  __syncthreads();
  if (tid == 0) { cinc(cnt_pre); cwait(cnt_pre, 8u); }
  __syncthreads();
  #pragma unroll
  for (int i = 0; i < 2; ++i) {
    int idx = i * NTHR + tid;            // 1024 = 8b x 128n
    int bb = idx >> 7, n = idx & 127;
    uint32_t v = ard(ws + E_OFF + ((size_t)g * 8 + bb) * 128 + n);
    sm.E[bb][n] = __builtin_bit_cast(float, v);
  }
  __syncthreads();

  const float S0 = sm.S0s;

  for (int t = 0; t < NT; ++t) {
    const int par = t & 1;
    // ---------- sync1 + read exchanged h,c ----------
    if (t > 0) {
      if (tid == 0) cwait(cnt1, 8u * (uint32_t)t);
      __syncthreads();
    }
    {
      uint32_t* hcb = ws + HC_OFF + ((size_t)par * NGRP + g) * 2048;
      #pragma unroll
      for (int i = 0; i < 4; ++i) {
        int w = i * NTHR + tid;          // [gid'(8)][b(8)][u5(32)]
        uint32_t v = ard(hcb + w);
        f16x2 pv = __builtin_bit_cast(f16x2, v);
        int gw = w >> 8, bb = (w >> 5) & 7, u5 = w & 31;
        int u = gw * UPW + u5;
        sm.hch[bb][u] = pv.x;
        sm.hch[bb][256 + u] = pv.y;
        sm.act[bb][128 + u] = pv.x;
      }
    }
    __syncthreads();
    // ---------- hpart -> P (own 16 t' rows, 8 b) ----------
    {
      const int ks = tid & 3, bb = (tid >> 2) & 7, lt = tid >> 5;
      float acc = 0.f;
      const f16* arow = &sm.hch[bb][0];
      #pragma unroll
      for (int i = 0; i < 16; ++i) {
        int c = ks * 16 + i;
        float4 w4 = *(const float4*)&sm.WA[((size_t)lt * 64 + (c ^ (lt & 7))) * 8];
        float4 a4 = *(const float4*)&arow[c * 8];
        const f16x2* wp = (const f16x2*)&w4;
        const f16x2* ap = (const f16x2*)&a4;
        #pragma unroll
        for (int u = 0; u < 4; ++u) acc = dot2f(wp[u], ap[u], acc);
      }
      acc += __shfl_xor(acc, 1);
      acc += __shfl_xor(acc, 2);
      if (ks == 0) sm.Pown[lt][bb] = __expf(2.f * (acc + sm.bah[lt]));
    }
    __syncthreads();
    // ---------- score partials over own t' slice, publish ----------
    {
      const int n = tid & 127, bq = tid >> 7;    // batches bq and bq+4
      float e0 = sm.E[bq][n], e1 = sm.E[bq + 4][n];
      float s0 = 0.f, s1 = 0.f;
      #pragma unroll
      for (int lt = 0; lt < TPW; ++lt) {
        float w = sm.w2a[lt];
        float p0 = sm.Pown[lt][bq], p1 = sm.Pown[lt][bq + 4];
        s0 = fmaf(w, __builtin_amdgcn_rcpf(fmaf(p0, e0, 1.f)), s0);
        s1 = fmaf(w, __builtin_amdgcn_rcpf(fmaf(p1, e1, 1.f)), s1);
      }
      f16x2 pv = pk(s0, s1);
      awr(ws + SP_OFF + (((size_t)g * 8 + gid) * 128 + n) * 4 + bq,
          __builtin_bit_cast(uint32_t, pv));
    }
    __syncthreads();
    if (tid == 0) { cinc(cnt2); cwait(cnt2, 8u * (uint32_t)(t + 1)); }
    __syncthreads();
    // ---------- score sum + softmax + wx ----------
    {
      const int l = tid & 63, bb = tid >> 6;     // wave = batch elem
      const int bq = bb & 3, hi = bb >> 2;
      float sA = S0, sB = S0;
      #pragma unroll
      for (int w = 0; w < 8; ++w) {
        uint32_t vA = ard(ws + SP_OFF + (((size_t)g * 8 + w) * 128 + l) * 4 + bq);
        uint32_t vB = ard(ws + SP_OFF + (((size_t)g * 8 + w) * 128 + l + 64) * 4 + bq);
        f16x2 pA = __builtin_bit_cast(f16x2, vA);
        f16x2 pB = __builtin_bit_cast(f16x2, vB);
        sA -= (float)(hi ? pA.y : pA.x);
        sB -= (float)(hi ? pB.y : pB.x);
      }
      float m = fmaxf(sA, sB);
      #pragma unroll
      for (int o = 32; o; o >>= 1) m = fmaxf(m, __shfl_xor(m, o));
      float eA = __expf(sA - m), eB = __expf(sB - m);
      float ss = eA + eB;
      #pragma unroll
      for (int o = 32; o; o >>= 1) ss += __shfl_xor(ss, o);
      float rs = 1.f / ss;
      const float* xr = x + ((size_t)(bbase + bb) * NT + t) * NS;
      float wxA = eA * rs * xr[l], wxB = eB * rs * xr[l + 64];
      sm.act[bb][l] = (f16)wxA;
      sm.act[bb][l + 64] = (f16)wxB;
      if (bb == gid) {
        float* ow = out_iw + ((size_t)(bbase + bb) * NT + t) * NS;
        ow[l] = wxA; ow[l + 64] = wxB;
      }
    }
    __syncthreads();
    // ---------- gates: rows r, r+64 for batch bb ----------
    {
      const int bb = tid & 7, r = tid >> 3;
      float a0 = sm.gbias[r], a1 = sm.gbias[r + 64];
      const f16* av = &sm.act[bb][0];
      const int rx = r & 7;
      #pragma unroll 8
      for (int c = 0; c < 48; ++c) {
        int cs = c ^ rx;
        float4 v  = *(const float4*)&av[c * 8];
        float4 w0 = *(const float4*)&sm.WG[((size_t)r * 48 + cs) * 8];
        float4 w1 = *(const float4*)&sm.WG[(((size_t)r + 64) * 48 + cs) * 8];
        const f16x2* vp = (const f16x2*)&v;
        const f16x2* p0 = (const f16x2*)&w0;
        const f16x2* p1 = (const f16x2*)&w1;
        #pragma unroll
        for (int u = 0; u < 4; ++u) {
          a0 = dot2f(p0[u], vp[u], a0);
          a1 = dot2f(p1[u], vp[u], a1);
        }
      }
      sm.gacc[r][bb] = a0;
      sm.gacc[r + 64][bb] = a1;
    }
    __syncthreads();
    // ---------- LSTM pointwise + publish h,c ----------
    if (tid < 256) {
      const int bb = tid & 7, u5 = tid >> 3;
      float gi = sm.gacc[u5][bb],      gf = sm.gacc[32 + u5][bb];
      float gg = sm.gacc[64 + u5][bb], go = sm.gacc[96 + u5][bb];
      float ii = 1.f / (1.f + __expf(-gi));
      float ff = 1.f / (1.f + __expf(-gf));
      float gt = 1.f - 2.f / (1.f + __expf(2.f * gg));
      float oo = 1.f / (1.f + __expf(-go));
      float c2 = ff * sm.cbuf[u5][bb] + ii * gt;
      float h2 = oo * (1.f - 2.f / (1.f + __expf(2.f * c2)));
      sm.cbuf[u5][bb] = c2;
      out_ie[((size_t)(bbase + bb) * NT + t) * NH + u0 + u5] = h2;
      f16x2 pv = pk(h2, c2);
      uint32_t* dst = ws + HC_OFF + ((size_t)(1 - par) * NGRP + g) * 2048 +
                      ((size_t)gid * 8 + bb) * 32 + u5;
      awr(dst, __builtin_bit_cast(uint32_t, pv));
    }
    __syncthreads();   // per-wave vmcnt(0) before barrier => stores in L2
    if (tid == 0) cinc(cnt1);
  }
}

extern "C" void kernel_launch(void* const* d_in, const int* in_sizes, int n_in,
                              void* d_out, int out_size, void* d_ws, size_t ws_size,
                              hipStream_t stream) {
  const float* x    = (const float*)d_in[0];
  const float* W_ah = (const float*)d_in[1];
  const float* b_ah = (const float*)d_in[2];
  const float* W_ai = (const float*)d_in[3];
  const float* b_ai = (const float*)d_in[4];
  const float* W_a  = (const float*)d_in[5];
  const float* b_a  = (const float*)d_in[6];
  const float* W_ih = (const float*)d_in[7];
  const float* W_hh = (const float*)d_in[8];
  const float* b_ih = (const float*)d_in[9];
  const float* b_hh = (const float*)d_in[10];
  float* out_iw = (float*)d_out;
  float* out_ie = (float*)d_out + (size_t)NB * NT * NS;
  uint32_t* ws = (uint32_t*)d_ws;

  hipLaunchKernelGGL(enc_init, dim3(256), dim3(256), 0, stream, ws);
  hipLaunchKernelGGL(enc_main, dim3(NWG), dim3(NTHR), 0, stream,
                     x, W_ah, b_ah, W_ai, b_ai, W_a, b_a, W_ih, W_hh, b_ih, b_hh,
                     out_iw, out_ie, ws);
}

// Round 5
// 854.550 us; speedup vs baseline: 1.6927x; 1.6927x over previous
//
#include <hip/hip_runtime.h>
#include <cstdint>

#define NB 256
#define NT 128
#define NS 128
#define NH 256

#define NTHR 512
#define NWG  256
#define NGRP 32
#define GBAT 8      // batch elems per group
#define UPW  32     // hidden units per wg
#define TPW  16     // W_ah rows per wg

// ws layout in uint32 words
#define HC_OFF  0        // [2][32][8 gid][8 b][32 u] = 131072 words (f16x2 h,c)
#define SP_OFF  131072   // [32][8 gid][128 n][4 bq]  = 131072 words (f16x2 sp_b, sp_b+4)
#define E_OFF   262144   // [32][8 b][128 n] f32      = 32768 words
#define CNT_OFF 294912   // [32][16] counters: [0]=pre [1]=c1 [2]=c2

typedef _Float16 f16;
typedef _Float16 f16x2 __attribute__((ext_vector_type(2)));
typedef _Float16 f16x8 __attribute__((ext_vector_type(8)));
typedef float    f32x4 __attribute__((ext_vector_type(4)));

__device__ __forceinline__ f16x2 pk(float a, float b) {
  f16x2 r; r.x = (f16)a; r.y = (f16)b; return r;
}
__device__ __forceinline__ f16x8 pack8(const float* s) {
  float4 v0 = *(const float4*)s, v1 = *(const float4*)(s + 4);
  f16x8 r;
  r[0] = (f16)v0.x; r[1] = (f16)v0.y; r[2] = (f16)v0.z; r[3] = (f16)v0.w;
  r[4] = (f16)v1.x; r[5] = (f16)v1.y; r[6] = (f16)v1.z; r[7] = (f16)v1.w;
  return r;
}
__device__ __forceinline__ void awr(uint32_t* p, uint32_t v) {
  __hip_atomic_store(p, v, __ATOMIC_RELAXED, __HIP_MEMORY_SCOPE_AGENT);
}
__device__ __forceinline__ uint32_t ard(uint32_t* p) {
  return __hip_atomic_load(p, __ATOMIC_RELAXED, __HIP_MEMORY_SCOPE_AGENT);
}
__device__ __forceinline__ void cinc(uint32_t* p) {
  __hip_atomic_fetch_add(p, 1u, __ATOMIC_RELAXED, __HIP_MEMORY_SCOPE_AGENT);
}
__device__ __forceinline__ void cwait(uint32_t* p, uint32_t tgt) {
  while (ard(p) < tgt) __builtin_amdgcn_s_sleep(2);
}

struct __align__(16) Sm {
  f16   ahc[16 * 512];    // A for hpart: [m=16 pad][k=512 (h|c)], 16B-chunk XOR-swizzled by m&7
  f16   agx[16 * 384];    // A for gates: [m=16 pad][k=384 (wx|h)], swizzled
  float pc[8 * 16 * 17];  // hpart K-partials [ks][t'l][m], pad 17
  float P[16 * 8];        // exp(2*hpart): [t'l][b]
  float E[8 * 128];       // exp(2*ipart): [b][n]
  float gacc[128 * 12];   // gate sums [lr][b], pad 12
  float gbias[128];
  float cbuf[32 * 8];     // [ul][b]
  float w2a[TPW], bah[TPW];
  float S0s;
};

__global__ void enc_init(uint32_t* ws) {
  int i = blockIdx.x * blockDim.x + threadIdx.x;
  if (i < 65536) ws[HC_OFF + i] = 0u;     // zero h,c parity 0
  if (i < 512)   ws[CNT_OFF + i] = 0u;    // zero counters
}

__global__ __launch_bounds__(NTHR, 2) void enc_main(
    const float* __restrict__ x,    const float* __restrict__ W_ah,
    const float* __restrict__ b_ah, const float* __restrict__ W_ai,
    const float* __restrict__ b_ai, const float* __restrict__ W_a,
    const float* __restrict__ b_a,  const float* __restrict__ W_ih,
    const float* __restrict__ W_hh, const float* __restrict__ b_ih,
    const float* __restrict__ b_hh, float* __restrict__ out_iw,
    float* __restrict__ out_ie,     uint32_t* __restrict__ ws)
{
  __shared__ Sm sm;
  const int tid  = threadIdx.x;
  const int wg   = blockIdx.x;
  const int xcd  = wg & 7, slot = wg >> 3;
  const int g    = xcd * 4 + (slot >> 3);   // group 0..31 (co-XCD if round-robin; perf-only)
  const int gid  = slot & 7;                // member 0..7
  const int bbase = g * GBAT;
  const int u0    = gid * UPW;

  const int wv = tid >> 6, ln = tid & 63;
  const int bn = ln & 15, kq = ln >> 4;     // frag row/col & k-quad

  uint32_t* cnt_pre = ws + CNT_OFF + g * 16 + 0;
  uint32_t* cnt1    = ws + CNT_OFF + g * 16 + 1;
  uint32_t* cnt2    = ws + CNT_OFF + g * 16 + 2;

  // ---- persistent weight B-fragments in registers ----
  // gates: wave wv owns local rows lr = wv*16 + bn  (gate = wv>>1, unit = u0 + (wv&1)*16 + bn)
  f16x8 wfrag[12];
  {
    const int grow = (wv >> 1) * 256 + u0 + (wv & 1) * 16 + bn;
    #pragma unroll
    for (int kk = 0; kk < 4; ++kk)
      wfrag[kk] = pack8(W_ih + (size_t)grow * NS + kk * 32 + kq * 8);
    #pragma unroll
    for (int kk = 4; kk < 12; ++kk)
      wfrag[kk] = pack8(W_hh + (size_t)grow * NH + (kk - 4) * 32 + kq * 8);
  }
  // hpart: wg owns t' rows gid*16..+15; wave wv owns K-slice [wv*64, wv*64+64)
  f16x8 ahfrag[2];
  {
    const int trow = gid * TPW + bn;
    #pragma unroll
    for (int j = 0; j < 2; ++j)
      ahfrag[j] = pack8(W_ah + (size_t)trow * 512 + wv * 64 + j * 32 + kq * 8);
  }

  // ---- LDS init ----
  for (int i = tid; i < 16 * 512; i += NTHR) sm.ahc[i] = (f16)0.f;
  for (int i = tid; i < 16 * 384; i += NTHR) sm.agx[i] = (f16)0.f;
  if (tid < 128) {
    int grow = (tid >> 5) * 256 + u0 + (tid & 31);
    sm.gbias[tid] = b_ih[grow] + b_hh[grow];
  }
  if (tid < TPW) {
    sm.w2a[tid] = 2.f * W_a[gid * TPW + tid];
    sm.bah[tid] = b_ah[gid * TPW + tid];
  }
  if (tid < 256) sm.cbuf[tid] = 0.f;
  if (tid == 0) { float s = b_a[0]; for (int i = 0; i < 128; ++i) s += W_a[i]; sm.S0s = s; }

  // ---- E for own batch elem (b = bbase+gid), publish, group barrier ----
  {
    int n = tid >> 2, ks = tid & 3;
    const float* xb = x + (size_t)(bbase + gid) * NT * NS;
    float a = 0.f;
    for (int tt = ks * 32; tt < ks * 32 + 32; ++tt)
      a = fmaf(xb[(size_t)tt * NS + n], W_ai[tt], a);
    a += __shfl_xor(a, 1); a += __shfl_xor(a, 2);
    if (ks == 0) {
      float e = __expf(2.f * (a + b_ai[0]));
      awr(ws + E_OFF + ((size_t)g * 8 + gid) * 128 + n, __builtin_bit_cast(uint32_t, e));
    }
  }
  __syncthreads();
  if (tid == 0) { cinc(cnt_pre); cwait(cnt_pre, 8u); }
  __syncthreads();
  #pragma unroll
  for (int i = 0; i < 2; ++i) {
    int idx = i * NTHR + tid;
    int bb = idx >> 7, n = idx & 127;
    uint32_t v = ard(ws + E_OFF + ((size_t)g * 8 + bb) * 128 + n);
    sm.E[bb * 128 + n] = __builtin_bit_cast(float, v);
  }
  __syncthreads();

  const float S0 = sm.S0s;

  for (int t = 0; t < NT; ++t) {
    const int par = t & 1;
    // ---------- sync + read exchanged h,c into swizzled A buffers ----------
    if (t > 0) {
      if (tid == 0) cwait(cnt1, 8u * (uint32_t)t);
      __syncthreads();
    }
    {
      uint32_t* hcb = ws + HC_OFF + ((size_t)par * NGRP + g) * 2048;
      #pragma unroll
      for (int i = 0; i < 4; ++i) {
        int w = i * NTHR + tid;          // [gid'(8)][b(8)][u5(32)]
        uint32_t v = ard(hcb + w);
        f16x2 pv = __builtin_bit_cast(f16x2, v);
        int gw = w >> 8, bb = (w >> 5) & 7, u5 = w & 31;
        int u = gw * UPW + u5;
        int ch = (u >> 3) ^ (bb & 7), off = u & 7;
        sm.ahc[bb * 512 + (ch << 3) + off] = pv.x;          // h -> ahc cols 0..255
        sm.ahc[bb * 512 + 256 + (ch << 3) + off] = pv.y;    // c -> ahc cols 256..511
        sm.agx[bb * 384 + 128 + (ch << 3) + off] = pv.x;    // h -> agx cols 128..383
      }
    }
    __syncthreads();
    // ---------- hpart MFMA: wave's K-slice; partials to pc ----------
    {
      f32x4 acc = {0.f, 0.f, 0.f, 0.f};
      #pragma unroll
      for (int j = 0; j < 2; ++j) {
        int chunk = wv * 8 + j * 4 + kq;
        f16x8 a = *(const f16x8*)&sm.ahc[bn * 512 + ((chunk ^ (bn & 7)) << 3)];
        acc = __builtin_amdgcn_mfma_f32_16x16x32_f16(a, ahfrag[j], acc, 0, 0, 0);
      }
      if (ln < 32) {
        #pragma unroll
        for (int r = 0; r < 4; ++r)
          sm.pc[wv * 272 + bn * 17 + (ln >> 4) * 4 + r] = acc[r];
      }
    }
    __syncthreads();
    // ---------- reduce K-partials + exp -> P ----------
    if (tid < 128) {
      int tl = tid & 15, mb = tid >> 4;    // mb = batch 0..7
      float s = 0.f;
      #pragma unroll
      for (int ks = 0; ks < 8; ++ks) s += sm.pc[ks * 272 + tl * 17 + mb];
      sm.P[tl * 8 + mb] = __expf(2.f * (s + sm.bah[tl]));
    }
    __syncthreads();
    // ---------- score partials over own t' slice, publish ----------
    {
      const int n = tid & 127, bq = tid >> 7;    // batches bq and bq+4
      float e0 = sm.E[bq * 128 + n], e1 = sm.E[(bq + 4) * 128 + n];
      float s0 = 0.f, s1 = 0.f;
      #pragma unroll
      for (int lt = 0; lt < TPW; ++lt) {
        float w = sm.w2a[lt];
        float p0 = sm.P[lt * 8 + bq], p1 = sm.P[lt * 8 + bq + 4];
        s0 = fmaf(w, __builtin_amdgcn_rcpf(fmaf(p0, e0, 1.f)), s0);
        s1 = fmaf(w, __builtin_amdgcn_rcpf(fmaf(p1, e1, 1.f)), s1);
      }
      awr(ws + SP_OFF + (((size_t)g * 8 + gid) * 128 + n) * 4 + bq,
          __builtin_bit_cast(uint32_t, pk(s0, s1)));
    }
    __syncthreads();
    if (tid == 0) { cinc(cnt2); cwait(cnt2, 8u * (uint32_t)(t + 1)); }
    __syncthreads();
    // ---------- score sum + softmax + wx (wave = batch elem) ----------
    {
      const int l = ln, bb = wv;
      const int bq = bb & 3, hi = bb >> 2;
      float sA = S0, sB = S0;
      #pragma unroll
      for (int w = 0; w < 8; ++w) {
        uint32_t vA = ard(ws + SP_OFF + (((size_t)g * 8 + w) * 128 + l) * 4 + bq);
        uint32_t vB = ard(ws + SP_OFF + (((size_t)g * 8 + w) * 128 + l + 64) * 4 + bq);
        f16x2 pA = __builtin_bit_cast(f16x2, vA);
        f16x2 pB = __builtin_bit_cast(f16x2, vB);
        sA -= (float)(hi ? pA.y : pA.x);
        sB -= (float)(hi ? pB.y : pB.x);
      }
      float m = fmaxf(sA, sB);
      #pragma unroll
      for (int o = 32; o; o >>= 1) m = fmaxf(m, __shfl_xor(m, o));
      float eA = __expf(sA - m), eB = __expf(sB - m);
      float ss = eA + eB;
      #pragma unroll
      for (int o = 32; o; o >>= 1) ss += __shfl_xor(ss, o);
      float rs = 1.f / ss;
      const float* xr = x + ((size_t)(bbase + bb) * NT + t) * NS;
      float wxA = eA * rs * xr[l], wxB = eB * rs * xr[l + 64];
      int sw = bb & 7;
      sm.agx[bb * 384 + (((l >> 3) ^ sw) << 3) + (l & 7)] = (f16)wxA;
      sm.agx[bb * 384 + ((((l + 64) >> 3) ^ sw) << 3) + (l & 7)] = (f16)wxB;
      if (bb == gid) {
        float* ow = out_iw + ((size_t)(bbase + bb) * NT + t) * NS;
        ow[l] = wxA; ow[l + 64] = wxB;
      }
    }
    __syncthreads();
    // ---------- gates MFMA: 12 K-steps, weights in registers ----------
    {
      f32x4 acc = {0.f, 0.f, 0.f, 0.f};
      #pragma unroll
      for (int kk = 0; kk < 12; ++kk) {
        int chunk = kk * 4 + kq;
        f16x8 a = *(const f16x8*)&sm.agx[bn * 384 + ((chunk ^ (bn & 7)) << 3)];
        acc = __builtin_amdgcn_mfma_f32_16x16x32_f16(a, wfrag[kk], acc, 0, 0, 0);
      }
      if (ln < 32)
        *(f32x4*)&sm.gacc[(wv * 16 + bn) * 12 + (ln >> 4) * 4] = acc;
    }
    __syncthreads();
    // ---------- LSTM pointwise + publish h,c ----------
    if (tid < 256) {
      const int b = tid & 7, ul = tid >> 3;
      float gi = sm.gacc[ul * 12 + b]          + sm.gbias[ul];
      float gf = sm.gacc[(32 + ul) * 12 + b]   + sm.gbias[32 + ul];
      float gg = sm.gacc[(64 + ul) * 12 + b]   + sm.gbias[64 + ul];
      float go = sm.gacc[(96 + ul) * 12 + b]   + sm.gbias[96 + ul];
      float ii = 1.f / (1.f + __expf(-gi));
      float ff = 1.f / (1.f + __expf(-gf));
      float gt = 1.f - 2.f / (1.f + __expf(2.f * gg));
      float oo = 1.f / (1.f + __expf(-go));
      float c2 = ff * sm.cbuf[ul * 8 + b] + ii * gt;
      float h2 = oo * (1.f - 2.f / (1.f + __expf(2.f * c2)));
      sm.cbuf[ul * 8 + b] = c2;
      out_ie[((size_t)(bbase + b) * NT + t) * NH + u0 + ul] = h2;
      uint32_t* dst = ws + HC_OFF + ((size_t)(1 - par) * NGRP + g) * 2048 +
                      ((size_t)gid * 8 + b) * 32 + ul;
      awr(dst, __builtin_bit_cast(uint32_t, pk(h2, c2)));
    }
    __syncthreads();   // drain stores before flag
    if (tid == 0) cinc(cnt1);
  }
}

extern "C" void kernel_launch(void* const* d_in, const int* in_sizes, int n_in,
                              void* d_out, int out_size, void* d_ws, size_t ws_size,
                              hipStream_t stream) {
  const float* x    = (const float*)d_in[0];
  const float* W_ah = (const float*)d_in[1];
  const float* b_ah = (const float*)d_in[2];
  const float* W_ai = (const float*)d_in[3];
  const float* b_ai = (const float*)d_in[4];
  const float* W_a  = (const float*)d_in[5];
  const float* b_a  = (const float*)d_in[6];
  const float* W_ih = (const float*)d_in[7];
  const float* W_hh = (const float*)d_in[8];
  const float* b_ih = (const float*)d_in[9];
  const float* b_hh = (const float*)d_in[10];
  float* out_iw = (float*)d_out;
  float* out_ie = (float*)d_out + (size_t)NB * NT * NS;
  uint32_t* ws = (uint32_t*)d_ws;

  hipLaunchKernelGGL(enc_init, dim3(256), dim3(256), 0, stream, ws);
  hipLaunchKernelGGL(enc_main, dim3(NWG), dim3(NTHR), 0, stream,
                     x, W_ah, b_ah, W_ai, b_ai, W_a, b_a, W_ih, W_hh, b_ih, b_hh,
                     out_iw, out_ie, ws);
}